// Round 15
// baseline (339.642 us; speedup 1.0000x reference)
//
#include <hip/hip_runtime.h>

// ---------------------------------------------------------------------------
// SelfAttention with KV cache, MI355X (gfx950).
// B=4, T=2048, C=1024, T_PAST=2048, T_TOT=4096.
// Mask tril(ones(T, T_total)) -> row t attends j<=t only => only past_k/v.
// Launches (main path, 4) [R13 base; R14 group-major LDS reverted -- it broke
// global coalescing (conflicts hit 0 but TA merge died, +85us)]:
//   1. prep: cvt x,Wq,Wk,Wv,past_k->bf16 (+ fused past_k->outK f32 copy)
//            + past_v->outV copy + VT bf16 transpose
//   2. proj_qkv (v2): Q->qb; V_new->outV[2048+); K_new->outK[2048+)
//   3. score_gemm (v2): P16 = bf16(exp(Q.kb^T - 16)) + row partial sums [LPT]
//   4. pv_gemm (v2): out = (P16 @ VT) / rowsum  [LPT]
//
// GEMM core v2 (this round: 2-slot ring, 5 blocks/CU): 128x128 tile, BK=32,
// 4 waves, 2-slot LDS ring (32KB -> 5 blocks/CU = 20 waves, was 3 slots/48KB/
// 12 waves; proj was latency/barrier-bound with nothing >35% busy, so raise
// TLP). Counted vmcnt(4) mid-loop (depth-1, never drains to 0), raw s_barrier
// pairs, XOR read-swizzle with pre-swizzled COALESCED global source (4 lanes
// = 64B run), lgkmcnt(0)+sched_barrier fence, setprio(1) around MFMA cluster.
// ---------------------------------------------------------------------------

typedef __bf16 bf16x8 __attribute__((ext_vector_type(8)));
typedef float f32x4 __attribute__((ext_vector_type(4)));

#define BB   4
#define TQ   2048
#define CD   1024
#define TPAST 2048
#define TTOT 4096
#define MROWS (BB * TQ)        // 8192
#define SSTRIDE_FALLBACK ((size_t)TTOT * CD * 2)  // u16 per batch window
#define SLOTU 8192             // u16 per ring slot (A 8KB + B 8KB)

__device__ __forceinline__ unsigned short f32_to_bf16u(float f) {
  unsigned int u = __float_as_uint(f);
  u += 0x7FFFu + ((u >> 16) & 1u);       // RNE
  return (unsigned short)(u >> 16);
}
__device__ __forceinline__ float bf16u_to_f32(unsigned short h) {
  unsigned int u = ((unsigned int)h) << 16;
  return __uint_as_float(u);
}
__device__ __forceinline__ unsigned int pack_bf16(float a, float b) {
  return (unsigned int)f32_to_bf16u(a) | ((unsigned int)f32_to_bf16u(b) << 16);
}
__device__ __forceinline__ void nt_store4(float4 f, float* p) {
  f32x4 v;
  v[0] = f.x; v[1] = f.y; v[2] = f.z; v[3] = f.w;
  __builtin_nontemporal_store(v, (f32x4*)p);
}

// async global->LDS, 16B per lane; LDS dest = wave-uniform base + lane*16
__device__ __forceinline__ void gload_lds16(const unsigned short* g,
                                            unsigned short* l) {
  __builtin_amdgcn_global_load_lds(
      (const __attribute__((address_space(1))) void*)g,
      (__attribute__((address_space(3))) void*)l, 16, 0, 0);
}

// ===========================================================================
// v2 core: 128x128, BK=32, 4 waves, 2-slot ring, 5 blocks/CU.
// ===========================================================================
struct StagePtrs { const unsigned short *a0, *a1, *b0, *b1; };

__device__ __forceinline__ void stage_step(StagePtrs& p, unsigned short* lds,
                                           int stOff, int wv) {
  unsigned short* base = lds + stOff + wv * 512;
  gload_lds16(p.a0, base);
  gload_lds16(p.a1, base + 2048);
  gload_lds16(p.b0, base + 4096);
  gload_lds16(p.b1, base + 6144);
  p.a0 += 32; p.a1 += 32; p.b0 += 32; p.b1 += 32;
}

__device__ __forceinline__ void gemm_core_v2(
    StagePtrs p, unsigned short* lds, int NT,
    int wr, int wc, int lane, int wv, f32x4 acc[4][4]) {
  const int gph8 = (((lane >> 4) ^ (lane & 3))) * 8;
  const int aRd = (wr * 64 + (lane & 15)) * 32 + gph8;
  const int bRd = 4096 + (wc * 64 + (lane & 15)) * 32 + gph8;
  stage_step(p, lds, 0, wv);                      // prologue: slot 0
  for (int t = 0; t < NT; ++t) {
    const int rdOff = (t & 1) * SLOTU;
    if (t + 1 < NT) stage_step(p, lds, (~t & 1) * SLOTU, wv);
    if (t + 1 < NT) asm volatile("s_waitcnt vmcnt(4)" ::: "memory");
    else            asm volatile("s_waitcnt vmcnt(0)" ::: "memory");
    asm volatile("s_barrier" ::: "memory");       // B1: slot t resident
    bf16x8 af[4], bg[4];
#pragma unroll
    for (int i = 0; i < 4; ++i)
      af[i] = *(const bf16x8*)&lds[rdOff + aRd + i * 512];
#pragma unroll
    for (int i = 0; i < 4; ++i)
      bg[i] = *(const bf16x8*)&lds[rdOff + bRd + i * 512];
    asm volatile("s_waitcnt lgkmcnt(0)" ::: "memory");
    __builtin_amdgcn_sched_barrier(0);
    asm volatile("s_barrier" ::: "memory");       // B2: slot released
    __builtin_amdgcn_s_setprio(1);
#pragma unroll
    for (int mi = 0; mi < 4; ++mi)
#pragma unroll
      for (int ni = 0; ni < 4; ++ni)
        acc[mi][ni] = __builtin_amdgcn_mfma_f32_16x16x32_bf16(
            af[mi], bg[ni], acc[mi][ni], 0, 0, 0);
    __builtin_amdgcn_s_setprio(0);
  }
}

// per-thread pre-swizzled source pointer (coalesced: 4 lanes = one 64B row).
__device__ __forceinline__ const unsigned short* swz_src(
    const unsigned short* base, size_t rowStart, size_t ld,
    int part, int wv, int lane) {
  int row = part * 64 + wv * 16 + (lane >> 2);
  int gp = (lane & 3) ^ ((lane >> 2) & 3);
  return base + (rowStart + row) * ld + gp * 8;
}

// ---- merged prep: v_copy_transpose blocks + cvt blocks (+pk f32 copy) ------
#define TP_PAD 134
#define VCT_BLOCKS 2048           // (2048/32) * (1024/128) * 4
#define R0_END 2097152            // x     : 8192*1024/4 f4
#define R1_END 2359296            // Wq    : +262144
#define R2_END 2621440            // Wk
#define R3_END 2883584            // Wv
#define R4_END 4980736            // past_k: +2097152
__global__ __launch_bounds__(256) void prep(
    const float* __restrict__ x, const float* __restrict__ wq,
    const float* __restrict__ wk, const float* __restrict__ wv,
    const float* __restrict__ pk, const float* __restrict__ pV,
    unsigned short* __restrict__ xb, unsigned short* __restrict__ wqb,
    unsigned short* __restrict__ wkb, unsigned short* __restrict__ wvb,
    unsigned short* __restrict__ kb,
    float* __restrict__ outV, unsigned short* __restrict__ VT,
    float* __restrict__ outKcopy) {   // nullptr -> skip pk f32 copy
  const int tid = threadIdx.x;
  if (blockIdx.x < VCT_BLOCKS) {
    __shared__ unsigned short T[32 * TP_PAD];
    const int bid = blockIdx.x;
    const int s0 = (bid & 63) * 32, c0 = ((bid >> 6) & 7) * 128, b = bid >> 9;
    const int s = tid >> 3, i8 = tid & 7;
    const float* src = &pV[(size_t)(b * TPAST + s0 + s) * CD + c0];
    float* dst = &outV[(size_t)b * (TTOT * CD) + (size_t)(s0 + s) * CD + c0];
#pragma unroll
    for (int k = 0; k < 4; ++k) {
      int c = k * 32 + i8 * 4;
      float4 f = *(const float4*)&src[c];
      nt_store4(f, &dst[c]);                  // pure output
      *(unsigned int*)&T[s * TP_PAD + c]     = pack_bf16(f.x, f.y);
      *(unsigned int*)&T[s * TP_PAD + c + 2] = pack_bf16(f.z, f.w);
    }
    __syncthreads();
    const int c = tid >> 2, sq = tid & 3;
#pragma unroll
    for (int ii = 0; ii < 2; ++ii) {
      int cc = c + ii * 64;
      unsigned short tmp[8];
#pragma unroll
      for (int j = 0; j < 8; ++j) tmp[j] = T[(sq * 8 + j) * TP_PAD + cc];
      *(uint4*)&VT[(size_t)(b * CD + c0 + cc) * TPAST + s0 + sq * 8] = *(uint4*)tmp;
    }
    return;
  }
  int i = (blockIdx.x - VCT_BLOCKS) * 256 + tid;
  const float* src; unsigned short* dst; int off;
  bool isPk = false;
  if (i < R0_END)      { src = x;  dst = xb;  off = i; }
  else if (i < R1_END) { src = wq; dst = wqb; off = i - R0_END; }
  else if (i < R2_END) { src = wk; dst = wkb; off = i - R1_END; }
  else if (i < R3_END) { src = wv; dst = wvb; off = i - R2_END; }
  else                 { src = pk; dst = kb;  off = i - R3_END; isPk = true; }
  float4 f = ((const float4*)src)[off];
  uint2 o;
  o.x = pack_bf16(f.x, f.y);
  o.y = pack_bf16(f.z, f.w);
  ((uint2*)dst)[off] = o;
  if (isPk && outKcopy) {
    int b = off >> 19;                 // 524288 f4-units per batch
    int rem = off & 524287;
    nt_store4(f, outKcopy + ((size_t)b * 1048576 + rem) * 4); // rows [0,2048)
  }
}

// ---- fallback: copy past_k into cache region rows [0,2048) -----------------
__global__ __launch_bounds__(256) void copy_past_kernel(
    const float* __restrict__ src, float* __restrict__ dst) {
  int i = blockIdx.x * 256 + threadIdx.x;      // float4 units
  int b = i >> 19;
  int rem = i & 524287;
  ((float4*)dst)[(size_t)b * 1048576 + rem] = ((const float4*)src)[i];
}

// ---- merged Q+V+K projection (v2 core) --------------------------------------
__global__ __launch_bounds__(256, 5) void proj_qkv(
    const unsigned short* __restrict__ A,    // x bf16 [8192][1024]
    const unsigned short* __restrict__ Wq_,
    const unsigned short* __restrict__ Wv_,
    const unsigned short* __restrict__ Wk_,
    const float* __restrict__ bq_, const float* __restrict__ bv_,
    const float* __restrict__ bk_,
    unsigned short* __restrict__ outQ,
    float* __restrict__ outV, float* __restrict__ outK) {
  __shared__ unsigned short lds[2 * SLOTU];
  const int tm = blockIdx.x * 128;
  const int which = blockIdx.y >> 3;         // 0=Q, 1=V, 2=K
  const int tn = (blockIdx.y & 7) * 128;
  const unsigned short* W = (which == 0) ? Wq_ : (which == 1) ? Wv_ : Wk_;
  const float* bias = (which == 0) ? bq_ : (which == 1) ? bv_ : bk_;
  const int tid = threadIdx.x, lane = tid & 63, wv = tid >> 6;
  const int wr = wv >> 1, wc = wv & 1;
  StagePtrs p;
  p.a0 = swz_src(A, tm, CD, 0, wv, lane);
  p.a1 = swz_src(A, tm, CD, 1, wv, lane);
  p.b0 = swz_src(W, tn, CD, 0, wv, lane);
  p.b1 = swz_src(W, tn, CD, 1, wv, lane);
  f32x4 acc[4][4] = {};
  gemm_core_v2(p, lds, CD / 32, wr, wc, lane, wv, acc);
  const int rsub = (lane >> 4) * 4, csub = lane & 15;
#pragma unroll
  for (int mi = 0; mi < 4; ++mi)
#pragma unroll
    for (int ni = 0; ni < 4; ++ni) {
      int gcn = tn + wc * 64 + ni * 16 + csub;
      float bvv = bias[gcn];
#pragma unroll
      for (int r = 0; r < 4; ++r) {
        int grw = tm + wr * 64 + mi * 16 + rsub + r;
        float v = acc[mi][ni][r] + bvv;
        if (which == 0) {
          outQ[(size_t)grw * CD + gcn] = f32_to_bf16u(v * 0.03125f);  // 1/sqrt(1024)
        } else {
          int b = grw >> 11, t = grw & (TQ - 1);
          float* o = (which == 1) ? outV : outK;
          __builtin_nontemporal_store(
              v, &o[(size_t)b * (TTOT * CD) + (size_t)(TPAST + t) * CD + gcn]);
        }
      }
    }
}

// ---- scores: P16 = bf16(exp(Q.kb^T - 16)), masked cols -> 0 (LPT) -----------
__global__ __launch_bounds__(256, 5) void score_gemm(
    const unsigned short* __restrict__ Q,
    const unsigned short* __restrict__ KB,
    unsigned short* __restrict__ S16, size_t sstride,
    float* __restrict__ l_part) {            // [4][2048][16] f32
  const int t0 = (TQ / 128 - 1 - blockIdx.x) * 128;
  const int s0 = blockIdx.y * 128, b = blockIdx.z;
  if (s0 > t0) return;                       // fully masked tile
  __shared__ unsigned short lds[2 * SLOTU];
  __shared__ float lpart[128][2];
  const int tid = threadIdx.x, lane = tid & 63, wv = tid >> 6;
  const int wr = wv >> 1, wc = wv & 1;
  StagePtrs p;
  p.a0 = swz_src(Q, (size_t)b * TQ + t0, CD, 0, wv, lane);
  p.a1 = swz_src(Q, (size_t)b * TQ + t0, CD, 1, wv, lane);
  p.b0 = swz_src(KB, (size_t)b * TPAST + s0, CD, 0, wv, lane);
  p.b1 = swz_src(KB, (size_t)b * TPAST + s0, CD, 1, wv, lane);
  f32x4 acc[4][4] = {};
  gemm_core_v2(p, lds, CD / 32, wr, wc, lane, wv, acc);
  const int rsub = (lane >> 4) * 4, csub = lane & 15;
  float rsum[4][4];
#pragma unroll
  for (int mi = 0; mi < 4; ++mi)
#pragma unroll
    for (int r = 0; r < 4; ++r) rsum[mi][r] = 0.f;
#pragma unroll
  for (int mi = 0; mi < 4; ++mi)
#pragma unroll
    for (int ni = 0; ni < 4; ++ni) {
      int gs = s0 + wc * 64 + ni * 16 + csub;
#pragma unroll
      for (int r = 0; r < 4; ++r) {
        int gt = t0 + wr * 64 + mi * 16 + rsub + r;
        float e = (gs <= gt) ? __expf(acc[mi][ni][r] - 16.f) : 0.f;
        unsigned short h = f32_to_bf16u(e);
        S16[(size_t)b * sstride + (size_t)gt * TPAST + gs] = h;
        rsum[mi][r] += bf16u_to_f32(h);      // match numerator quantization
      }
    }
#pragma unroll
  for (int mi = 0; mi < 4; ++mi)
#pragma unroll
    for (int r = 0; r < 4; ++r) {
      float v = rsum[mi][r];
      v += __shfl_xor(v, 1);
      v += __shfl_xor(v, 2);
      v += __shfl_xor(v, 4);
      v += __shfl_xor(v, 8);
      rsum[mi][r] = v;                       // sum over 16 csub lanes
    }
  if ((lane & 15) == 0) {
#pragma unroll
    for (int mi = 0; mi < 4; ++mi)
#pragma unroll
      for (int r = 0; r < 4; ++r)
        lpart[wr * 64 + mi * 16 + rsub + r][wc] = rsum[mi][r];
  }
  __syncthreads();
  if (tid < 128)
    l_part[((size_t)b * TQ + t0 + tid) * 16 + (s0 >> 7)] =
        lpart[tid][0] + lpart[tid][1];
}

// ---- out = (P16 @ VT) / rowsum (LPT) -----------------------------------------
__global__ __launch_bounds__(256, 5) void pv_gemm(
    const unsigned short* __restrict__ Pb,  // bf16 exp values
    const unsigned short* __restrict__ VT,  // bf16 [4][1024][2048]
    float* __restrict__ O, size_t sstride,
    const float* __restrict__ l_part) {
  const int t0 = (TQ / 128 - 1 - blockIdx.x) * 128;
  const int c0 = blockIdx.y * 128, b = blockIdx.z;
  __shared__ unsigned short lds[2 * SLOTU];
  const int tid = threadIdx.x, lane = tid & 63, wv = tid >> 6;
  const int wr = wv >> 1, wc = wv & 1;
  StagePtrs p;
  p.a0 = swz_src(Pb + (size_t)b * sstride, t0, TPAST, 0, wv, lane);
  p.a1 = swz_src(Pb + (size_t)b * sstride, t0, TPAST, 1, wv, lane);
  p.b0 = swz_src(VT, (size_t)b * CD + c0, TPAST, 0, wv, lane);
  p.b1 = swz_src(VT, (size_t)b * CD + c0, TPAST, 1, wv, lane);
  f32x4 acc[4][4] = {};
  const int s_end = (t0 + 128 < TPAST) ? (t0 + 128) : TPAST;  // P==0 past t
  gemm_core_v2(p, lds, s_end / 32, wr, wc, lane, wv, acc);
  // --- row normalization factors: 1 / sum_j l_part[b][t][j], j <= t0>>7 ---
  __syncthreads();
  float* linv = (float*)lds;                 // reuse ring LDS
  if (tid < 128) {
    const float* lp = &l_part[((size_t)b * TQ + t0 + tid) * 16];
    float s = 0.f;
    const int nj = (t0 >> 7) + 1;
    for (int j = 0; j < nj; ++j) s += lp[j];
    linv[tid] = 1.0f / s;
  }
  __syncthreads();
  const int rsub = (lane >> 4) * 4, csub = lane & 15;
#pragma unroll
  for (int mi = 0; mi < 4; ++mi)
#pragma unroll
    for (int ni = 0; ni < 4; ++ni) {
      int gcn = c0 + wc * 64 + ni * 16 + csub;
#pragma unroll
      for (int r = 0; r < 4; ++r) {
        int lrow = wr * 64 + mi * 16 + rsub + r;
        int gt = t0 + lrow;
        __builtin_nontemporal_store(
            acc[mi][ni][r] * linv[lrow], &O[(size_t)(b * TQ + gt) * CD + gcn]);
      }
    }
}

extern "C" void kernel_launch(void* const* d_in, const int* in_sizes, int n_in,
                              void* d_out, int out_size, void* d_ws, size_t ws_size,
                              hipStream_t stream) {
  const float* x  = (const float*)d_in[0];
  const float* pk = (const float*)d_in[1];
  const float* pv = (const float*)d_in[2];
  const float* Wq = (const float*)d_in[3];
  const float* bq = (const float*)d_in[4];
  const float* Wk = (const float*)d_in[5];
  const float* bk = (const float*)d_in[6];
  const float* Wv = (const float*)d_in[7];
  const float* bv = (const float*)d_in[8];

  float* out  = (float*)d_out;                       // (4,2048,1024)
  float* outK = out + (size_t)BB * TQ * CD;          // (4,4096,1024)
  float* outV = outK + (size_t)BB * TTOT * CD;       // (4,4096,1024)

  unsigned short* xb  = (unsigned short*)d_ws;       // 8192*1024 bf16
  unsigned short* wqb = xb + (size_t)MROWS * CD;
  unsigned short* wkb = wqb + (size_t)CD * CD;
  unsigned short* wvb = wkb + (size_t)CD * CD;
  unsigned short* qb  = wvb + (size_t)CD * CD;       // 8192*1024 bf16
  unsigned short* vtb = qb + (size_t)MROWS * CD;     // 4*1024*2048 bf16 (V^T)
  unsigned short* kb  = vtb + (size_t)BB * CD * TPAST; // 4*2048*1024 bf16
  unsigned short* wsEnd = kb + (size_t)BB * TPAST * CD;

  // S16 (4*2048*2048 bf16 = 33.5MB) + l_part (4*2048*16 f32 = 0.5MB)
  const size_t baseBytes = (size_t)((char*)wsEnd - (char*)d_ws);
  const size_t s16Bytes  = (size_t)BB * TQ * TPAST * 2;
  const size_t lpBytes   = (size_t)BB * TQ * 16 * 4;
  const bool fit = ws_size >= baseBytes + s16Bytes + lpBytes;

  unsigned short* S16;
  float* l_part;
  size_t sstride;
  if (fit) {
    S16 = wsEnd;
    l_part = (float*)(S16 + (size_t)BB * TQ * TPAST);
    sstride = (size_t)TQ * TPAST;            // dense per-batch stride
  } else {
    S16 = (unsigned short*)outK;             // overlay rows [0,2048)/batch
    l_part = (float*)wsEnd;
    sstride = SSTRIDE_FALLBACK;
  }

  // 1. conversions + past_v copy/transpose (+ past_k f32 copy when S16 in ws)
  prep<<<VCT_BLOCKS + R4_END / 256, 256, 0, stream>>>(
      x, Wq, Wk, Wv, pk, pv, xb, wqb, wkb, wvb, kb, outV, vtb,
      fit ? outK : nullptr);
  // 2. Q (bf16, scaled) + V_new + K_new (rows 2048+)
  proj_qkv<<<dim3(MROWS / 128, 24), 256, 0, stream>>>(
      xb, wqb, wvb, wkb, bq, bv, bk, qb, outV, outK);
  // 3. P16 = exp(scores - 16) + row partial sums (longest-first)
  score_gemm<<<dim3(TQ / 128, TPAST / 128, BB), 256, 0, stream>>>(
      qb, kb, S16, sstride, l_part);
  // 4. out = (P16 @ VT) / rowsum (longest-first)
  pv_gemm<<<dim3(TQ / 128, CD / 128, BB), 256, 0, stream>>>(
      S16, vtb, out, sstride, l_part);
  // 5. fallback only: past_k -> outK rows [0,2048) after pv consumed S16
  if (!fit)
    copy_past_kernel<<<BB * TPAST * CD / 4 / 256, 256, 0, stream>>>(pk, outK);
}

// Round 16
// 199.950 us; speedup vs baseline: 1.6986x; 1.6986x over previous
//
#include <hip/hip_runtime.h>

// ---------------------------------------------------------------------------
// SelfAttention with KV cache, MI355X (gfx950).
// B=4, T=2048, C=1024, T_PAST=2048, T_TOT=4096.
// Mask tril(ones(T, T_total)) -> row t attends j<=t only => only past_k/v.
// Launches (main path, 4) [R13 configuration — best measured, 200.8us.
// R14 (group-major LDS) and R15 (2-slot/5-block) both regressed; reverted]:
//   1. prep: cvt x,Wq,Wk,Wv,past_k->bf16 (+ fused past_k->outK f32 copy)
//            + past_v->outV copy + VT bf16 transpose
//   2. proj_qkv (v2): Q->qb; V_new->outV[2048+); K_new->outK[2048+)
//   3. score_gemm (v2): P16 = bf16(exp(Q.kb^T - 16)) + row partial sums [LPT]
//   4. pv_gemm (v2): out = (P16 @ VT) / rowsum  [LPT]
// Pure-output f32 stores use __builtin_nontemporal_store (never re-read);
// vector stores go through ext_vector f32x4 (HIP float4 class is rejected).
//
// GEMM core v2: 128x128 tile, BK=32, 4 waves, 3-slot LDS ring (48KB),
// counted vmcnt(8/4/0) never draining mid-loop, raw s_barrier pairs, XOR
// read-swizzle with pre-swizzled global source, lgkmcnt(0)+sched_barrier
// fence, setprio(1) around the MFMA cluster.  (proven R7-R13)
// ---------------------------------------------------------------------------

typedef __bf16 bf16x8 __attribute__((ext_vector_type(8)));
typedef float f32x4 __attribute__((ext_vector_type(4)));

#define BB   4
#define TQ   2048
#define CD   1024
#define TPAST 2048
#define TTOT 4096
#define MROWS (BB * TQ)        // 8192
#define SSTRIDE_FALLBACK ((size_t)TTOT * CD * 2)  // u16 per batch window
#define SLOTU 8192             // u16 per ring slot (A 8KB + B 8KB)

__device__ __forceinline__ unsigned short f32_to_bf16u(float f) {
  unsigned int u = __float_as_uint(f);
  u += 0x7FFFu + ((u >> 16) & 1u);       // RNE
  return (unsigned short)(u >> 16);
}
__device__ __forceinline__ float bf16u_to_f32(unsigned short h) {
  unsigned int u = ((unsigned int)h) << 16;
  return __uint_as_float(u);
}
__device__ __forceinline__ unsigned int pack_bf16(float a, float b) {
  return (unsigned int)f32_to_bf16u(a) | ((unsigned int)f32_to_bf16u(b) << 16);
}
__device__ __forceinline__ void nt_store4(float4 f, float* p) {
  f32x4 v;
  v[0] = f.x; v[1] = f.y; v[2] = f.z; v[3] = f.w;
  __builtin_nontemporal_store(v, (f32x4*)p);
}

// async global->LDS, 16B per lane; LDS dest = wave-uniform base + lane*16
__device__ __forceinline__ void gload_lds16(const unsigned short* g,
                                            unsigned short* l) {
  __builtin_amdgcn_global_load_lds(
      (const __attribute__((address_space(1))) void*)g,
      (__attribute__((address_space(3))) void*)l, 16, 0, 0);
}

// ===========================================================================
// v2 core: 128x128, BK=32, 4 waves, 3-slot ring. (proven R7-R13)
// ===========================================================================
struct StagePtrs { const unsigned short *a0, *a1, *b0, *b1; };

__device__ __forceinline__ void stage_step(StagePtrs& p, unsigned short* lds,
                                           int stOff, int wv) {
  unsigned short* base = lds + stOff + wv * 512;
  gload_lds16(p.a0, base);
  gload_lds16(p.a1, base + 2048);
  gload_lds16(p.b0, base + 4096);
  gload_lds16(p.b1, base + 6144);
  p.a0 += 32; p.a1 += 32; p.b0 += 32; p.b1 += 32;
}

__device__ __forceinline__ void gemm_core_v2(
    StagePtrs p, unsigned short* lds, int NT,
    int wr, int wc, int lane, int wv, f32x4 acc[4][4]) {
  const int gph8 = (((lane >> 4) ^ (lane & 3))) * 8;
  const int aRd = (wr * 64 + (lane & 15)) * 32 + gph8;
  const int bRd = 4096 + (wc * 64 + (lane & 15)) * 32 + gph8;
  stage_step(p, lds, 0, wv);
  stage_step(p, lds, SLOTU, wv);
  int stOff = 2 * SLOTU;
  int rdOff = 0;
  for (int t = 0; t < NT; ++t) {
    if (t + 2 < NT) {
      stage_step(p, lds, stOff, wv);
      stOff = (stOff == 2 * SLOTU) ? 0 : stOff + SLOTU;
    }
    const int rem = NT - 1 - t;
    if (rem >= 2)      asm volatile("s_waitcnt vmcnt(8)" ::: "memory");
    else if (rem == 1) asm volatile("s_waitcnt vmcnt(4)" ::: "memory");
    else               asm volatile("s_waitcnt vmcnt(0)" ::: "memory");
    asm volatile("s_barrier" ::: "memory");       // B1: slot t resident
    bf16x8 af[4], bg[4];
#pragma unroll
    for (int i = 0; i < 4; ++i)
      af[i] = *(const bf16x8*)&lds[rdOff + aRd + i * 512];
#pragma unroll
    for (int i = 0; i < 4; ++i)
      bg[i] = *(const bf16x8*)&lds[rdOff + bRd + i * 512];
    asm volatile("s_waitcnt lgkmcnt(0)" ::: "memory");
    __builtin_amdgcn_sched_barrier(0);
    asm volatile("s_barrier" ::: "memory");       // B2: slot released
    __builtin_amdgcn_s_setprio(1);
#pragma unroll
    for (int mi = 0; mi < 4; ++mi)
#pragma unroll
      for (int ni = 0; ni < 4; ++ni)
        acc[mi][ni] = __builtin_amdgcn_mfma_f32_16x16x32_bf16(
            af[mi], bg[ni], acc[mi][ni], 0, 0, 0);
    __builtin_amdgcn_s_setprio(0);
    rdOff = (rdOff == 2 * SLOTU) ? 0 : rdOff + SLOTU;
  }
}

// per-thread pre-swizzled source pointer for one operand tile.
__device__ __forceinline__ const unsigned short* swz_src(
    const unsigned short* base, size_t rowStart, size_t ld,
    int part, int wv, int lane) {
  int row = part * 64 + wv * 16 + (lane >> 2);
  int gp = (lane & 3) ^ ((lane >> 2) & 3);
  return base + (rowStart + row) * ld + gp * 8;
}

// ---- merged prep: v_copy_transpose blocks + cvt blocks (+pk f32 copy) ------
#define TP_PAD 134
#define VCT_BLOCKS 2048           // (2048/32) * (1024/128) * 4
#define R0_END 2097152            // x     : 8192*1024/4 f4
#define R1_END 2359296            // Wq    : +262144
#define R2_END 2621440            // Wk
#define R3_END 2883584            // Wv
#define R4_END 4980736            // past_k: +2097152
__global__ __launch_bounds__(256) void prep(
    const float* __restrict__ x, const float* __restrict__ wq,
    const float* __restrict__ wk, const float* __restrict__ wv,
    const float* __restrict__ pk, const float* __restrict__ pV,
    unsigned short* __restrict__ xb, unsigned short* __restrict__ wqb,
    unsigned short* __restrict__ wkb, unsigned short* __restrict__ wvb,
    unsigned short* __restrict__ kb,
    float* __restrict__ outV, unsigned short* __restrict__ VT,
    float* __restrict__ outKcopy) {   // nullptr -> skip pk f32 copy
  const int tid = threadIdx.x;
  if (blockIdx.x < VCT_BLOCKS) {
    __shared__ unsigned short T[32 * TP_PAD];
    const int bid = blockIdx.x;
    const int s0 = (bid & 63) * 32, c0 = ((bid >> 6) & 7) * 128, b = bid >> 9;
    const int s = tid >> 3, i8 = tid & 7;
    const float* src = &pV[(size_t)(b * TPAST + s0 + s) * CD + c0];
    float* dst = &outV[(size_t)b * (TTOT * CD) + (size_t)(s0 + s) * CD + c0];
#pragma unroll
    for (int k = 0; k < 4; ++k) {
      int c = k * 32 + i8 * 4;
      float4 f = *(const float4*)&src[c];
      nt_store4(f, &dst[c]);                  // pure output
      *(unsigned int*)&T[s * TP_PAD + c]     = pack_bf16(f.x, f.y);
      *(unsigned int*)&T[s * TP_PAD + c + 2] = pack_bf16(f.z, f.w);
    }
    __syncthreads();
    const int c = tid >> 2, sq = tid & 3;
#pragma unroll
    for (int ii = 0; ii < 2; ++ii) {
      int cc = c + ii * 64;
      unsigned short tmp[8];
#pragma unroll
      for (int j = 0; j < 8; ++j) tmp[j] = T[(sq * 8 + j) * TP_PAD + cc];
      *(uint4*)&VT[(size_t)(b * CD + c0 + cc) * TPAST + s0 + sq * 8] = *(uint4*)tmp;
    }
    return;
  }
  int i = (blockIdx.x - VCT_BLOCKS) * 256 + tid;
  const float* src; unsigned short* dst; int off;
  bool isPk = false;
  if (i < R0_END)      { src = x;  dst = xb;  off = i; }
  else if (i < R1_END) { src = wq; dst = wqb; off = i - R0_END; }
  else if (i < R2_END) { src = wk; dst = wkb; off = i - R1_END; }
  else if (i < R3_END) { src = wv; dst = wvb; off = i - R2_END; }
  else                 { src = pk; dst = kb;  off = i - R3_END; isPk = true; }
  float4 f = ((const float4*)src)[off];
  uint2 o;
  o.x = pack_bf16(f.x, f.y);
  o.y = pack_bf16(f.z, f.w);
  ((uint2*)dst)[off] = o;
  if (isPk && outKcopy) {
    int b = off >> 19;                 // 524288 f4-units per batch
    int rem = off & 524287;
    nt_store4(f, outKcopy + ((size_t)b * 1048576 + rem) * 4); // rows [0,2048)
  }
}

// ---- fallback: copy past_k into cache region rows [0,2048) -----------------
__global__ __launch_bounds__(256) void copy_past_kernel(
    const float* __restrict__ src, float* __restrict__ dst) {
  int i = blockIdx.x * 256 + threadIdx.x;      // float4 units
  int b = i >> 19;
  int rem = i & 524287;
  ((float4*)dst)[(size_t)b * 1048576 + rem] = ((const float4*)src)[i];
}

// ---- merged Q+V+K projection (v2 core) --------------------------------------
__global__ __launch_bounds__(256, 3) void proj_qkv(
    const unsigned short* __restrict__ A,    // x bf16 [8192][1024]
    const unsigned short* __restrict__ Wq_,
    const unsigned short* __restrict__ Wv_,
    const unsigned short* __restrict__ Wk_,
    const float* __restrict__ bq_, const float* __restrict__ bv_,
    const float* __restrict__ bk_,
    unsigned short* __restrict__ outQ,
    float* __restrict__ outV, float* __restrict__ outK) {
  __shared__ unsigned short lds[3 * SLOTU];
  const int tm = blockIdx.x * 128;
  const int which = blockIdx.y >> 3;         // 0=Q, 1=V, 2=K
  const int tn = (blockIdx.y & 7) * 128;
  const unsigned short* W = (which == 0) ? Wq_ : (which == 1) ? Wv_ : Wk_;
  const float* bias = (which == 0) ? bq_ : (which == 1) ? bv_ : bk_;
  const int tid = threadIdx.x, lane = tid & 63, wv = tid >> 6;
  const int wr = wv >> 1, wc = wv & 1;
  StagePtrs p;
  p.a0 = swz_src(A, tm, CD, 0, wv, lane);
  p.a1 = swz_src(A, tm, CD, 1, wv, lane);
  p.b0 = swz_src(W, tn, CD, 0, wv, lane);
  p.b1 = swz_src(W, tn, CD, 1, wv, lane);
  f32x4 acc[4][4] = {};
  gemm_core_v2(p, lds, CD / 32, wr, wc, lane, wv, acc);
  const int rsub = (lane >> 4) * 4, csub = lane & 15;
#pragma unroll
  for (int mi = 0; mi < 4; ++mi)
#pragma unroll
    for (int ni = 0; ni < 4; ++ni) {
      int gcn = tn + wc * 64 + ni * 16 + csub;
      float bvv = bias[gcn];
#pragma unroll
      for (int r = 0; r < 4; ++r) {
        int grw = tm + wr * 64 + mi * 16 + rsub + r;
        float v = acc[mi][ni][r] + bvv;
        if (which == 0) {
          outQ[(size_t)grw * CD + gcn] = f32_to_bf16u(v * 0.03125f);  // 1/sqrt(1024)
        } else {
          int b = grw >> 11, t = grw & (TQ - 1);
          float* o = (which == 1) ? outV : outK;
          __builtin_nontemporal_store(
              v, &o[(size_t)b * (TTOT * CD) + (size_t)(TPAST + t) * CD + gcn]);
        }
      }
    }
}

// ---- scores: P16 = bf16(exp(Q.kb^T - 16)), masked cols -> 0 -----------------
// Longest-row-first: t0 = (15 - bx)*128 (LPT scheduling for the causal skip).
__global__ __launch_bounds__(256, 3) void score_gemm(
    const unsigned short* __restrict__ Q,
    const unsigned short* __restrict__ KB,
    unsigned short* __restrict__ S16, size_t sstride,
    float* __restrict__ l_part) {            // [4][2048][16] f32
  const int t0 = (TQ / 128 - 1 - blockIdx.x) * 128;
  const int s0 = blockIdx.y * 128, b = blockIdx.z;
  if (s0 > t0) return;                       // fully masked tile
  __shared__ unsigned short lds[3 * SLOTU];
  __shared__ float lpart[128][2];
  const int tid = threadIdx.x, lane = tid & 63, wv = tid >> 6;
  const int wr = wv >> 1, wc = wv & 1;
  StagePtrs p;
  p.a0 = swz_src(Q, (size_t)b * TQ + t0, CD, 0, wv, lane);
  p.a1 = swz_src(Q, (size_t)b * TQ + t0, CD, 1, wv, lane);
  p.b0 = swz_src(KB, (size_t)b * TPAST + s0, CD, 0, wv, lane);
  p.b1 = swz_src(KB, (size_t)b * TPAST + s0, CD, 1, wv, lane);
  f32x4 acc[4][4] = {};
  gemm_core_v2(p, lds, CD / 32, wr, wc, lane, wv, acc);
  const int rsub = (lane >> 4) * 4, csub = lane & 15;
  float rsum[4][4];
#pragma unroll
  for (int mi = 0; mi < 4; ++mi)
#pragma unroll
    for (int r = 0; r < 4; ++r) rsum[mi][r] = 0.f;
#pragma unroll
  for (int mi = 0; mi < 4; ++mi)
#pragma unroll
    for (int ni = 0; ni < 4; ++ni) {
      int gs = s0 + wc * 64 + ni * 16 + csub;
#pragma unroll
      for (int r = 0; r < 4; ++r) {
        int gt = t0 + wr * 64 + mi * 16 + rsub + r;
        float e = (gs <= gt) ? __expf(acc[mi][ni][r] - 16.f) : 0.f;
        unsigned short h = f32_to_bf16u(e);
        S16[(size_t)b * sstride + (size_t)gt * TPAST + gs] = h;
        rsum[mi][r] += bf16u_to_f32(h);      // match numerator quantization
      }
    }
#pragma unroll
  for (int mi = 0; mi < 4; ++mi)
#pragma unroll
    for (int r = 0; r < 4; ++r) {
      float v = rsum[mi][r];
      v += __shfl_xor(v, 1);
      v += __shfl_xor(v, 2);
      v += __shfl_xor(v, 4);
      v += __shfl_xor(v, 8);
      rsum[mi][r] = v;                       // sum over 16 csub lanes
    }
  if ((lane & 15) == 0) {
#pragma unroll
    for (int mi = 0; mi < 4; ++mi)
#pragma unroll
      for (int r = 0; r < 4; ++r)
        lpart[wr * 64 + mi * 16 + rsub + r][wc] = rsum[mi][r];
  }
  __syncthreads();
  if (tid < 128)
    l_part[((size_t)b * TQ + t0 + tid) * 16 + (s0 >> 7)] =
        lpart[tid][0] + lpart[tid][1];
}

// ---- out = (P16 @ VT) / rowsum (v2 core) ------------------------------------
// Longest-K-first: t0 = (15 - bx)*128 (K extent = t0+128; LPT scheduling).
__global__ __launch_bounds__(256, 3) void pv_gemm(
    const unsigned short* __restrict__ Pb,  // bf16 exp values
    const unsigned short* __restrict__ VT,  // bf16 [4][1024][2048]
    float* __restrict__ O, size_t sstride,
    const float* __restrict__ l_part) {
  const int t0 = (TQ / 128 - 1 - blockIdx.x) * 128;
  const int c0 = blockIdx.y * 128, b = blockIdx.z;
  __shared__ unsigned short lds[3 * SLOTU];
  const int tid = threadIdx.x, lane = tid & 63, wv = tid >> 6;
  const int wr = wv >> 1, wc = wv & 1;
  StagePtrs p;
  p.a0 = swz_src(Pb + (size_t)b * sstride, t0, TPAST, 0, wv, lane);
  p.a1 = swz_src(Pb + (size_t)b * sstride, t0, TPAST, 1, wv, lane);
  p.b0 = swz_src(VT, (size_t)b * CD + c0, TPAST, 0, wv, lane);
  p.b1 = swz_src(VT, (size_t)b * CD + c0, TPAST, 1, wv, lane);
  f32x4 acc[4][4] = {};
  const int s_end = (t0 + 128 < TPAST) ? (t0 + 128) : TPAST;  // P==0 past t
  gemm_core_v2(p, lds, s_end / 32, wr, wc, lane, wv, acc);
  // --- row normalization factors: 1 / sum_j l_part[b][t][j], j <= t0>>7 ---
  __syncthreads();
  float* linv = (float*)lds;                 // reuse ring LDS
  if (tid < 128) {
    const float* lp = &l_part[((size_t)b * TQ + t0 + tid) * 16];
    float s = 0.f;
    const int nj = (t0 >> 7) + 1;
    for (int j = 0; j < nj; ++j) s += lp[j];
    linv[tid] = 1.0f / s;
  }
  __syncthreads();
  const int rsub = (lane >> 4) * 4, csub = lane & 15;
#pragma unroll
  for (int mi = 0; mi < 4; ++mi)
#pragma unroll
    for (int ni = 0; ni < 4; ++ni) {
      int gcn = c0 + wc * 64 + ni * 16 + csub;
#pragma unroll
      for (int r = 0; r < 4; ++r) {
        int lrow = wr * 64 + mi * 16 + rsub + r;
        int gt = t0 + lrow;
        __builtin_nontemporal_store(
            acc[mi][ni][r] * linv[lrow], &O[(size_t)(b * TQ + gt) * CD + gcn]);
      }
    }
}

extern "C" void kernel_launch(void* const* d_in, const int* in_sizes, int n_in,
                              void* d_out, int out_size, void* d_ws, size_t ws_size,
                              hipStream_t stream) {
  const float* x  = (const float*)d_in[0];
  const float* pk = (const float*)d_in[1];
  const float* pv = (const float*)d_in[2];
  const float* Wq = (const float*)d_in[3];
  const float* bq = (const float*)d_in[4];
  const float* Wk = (const float*)d_in[5];
  const float* bk = (const float*)d_in[6];
  const float* Wv = (const float*)d_in[7];
  const float* bv = (const float*)d_in[8];

  float* out  = (float*)d_out;                       // (4,2048,1024)
  float* outK = out + (size_t)BB * TQ * CD;          // (4,4096,1024)
  float* outV = outK + (size_t)BB * TTOT * CD;       // (4,4096,1024)

  unsigned short* xb  = (unsigned short*)d_ws;       // 8192*1024 bf16
  unsigned short* wqb = xb + (size_t)MROWS * CD;
  unsigned short* wkb = wqb + (size_t)CD * CD;
  unsigned short* wvb = wkb + (size_t)CD * CD;
  unsigned short* qb  = wvb + (size_t)CD * CD;       // 8192*1024 bf16
  unsigned short* vtb = qb + (size_t)MROWS * CD;     // 4*1024*2048 bf16 (V^T)
  unsigned short* kb  = vtb + (size_t)BB * CD * TPAST; // 4*2048*1024 bf16
  unsigned short* wsEnd = kb + (size_t)BB * TPAST * CD;

  // S16 (4*2048*2048 bf16 = 33.5MB) + l_part (4*2048*16 f32 = 0.5MB)
  const size_t baseBytes = (size_t)((char*)wsEnd - (char*)d_ws);
  const size_t s16Bytes  = (size_t)BB * TQ * TPAST * 2;
  const size_t lpBytes   = (size_t)BB * TQ * 16 * 4;
  const bool fit = ws_size >= baseBytes + s16Bytes + lpBytes;

  unsigned short* S16;
  float* l_part;
  size_t sstride;
  if (fit) {
    S16 = wsEnd;
    l_part = (float*)(S16 + (size_t)BB * TQ * TPAST);
    sstride = (size_t)TQ * TPAST;            // dense per-batch stride
  } else {
    S16 = (unsigned short*)outK;             // overlay rows [0,2048)/batch
    l_part = (float*)wsEnd;
    sstride = SSTRIDE_FALLBACK;
  }

  // 1. conversions + past_v copy/transpose (+ past_k f32 copy when S16 in ws)
  prep<<<VCT_BLOCKS + R4_END / 256, 256, 0, stream>>>(
      x, Wq, Wk, Wv, pk, pv, xb, wqb, wkb, wvb, kb, outV, vtb,
      fit ? outK : nullptr);
  // 2. Q (bf16, scaled) + V_new + K_new (rows 2048+)
  proj_qkv<<<dim3(MROWS / 128, 24), 256, 0, stream>>>(
      xb, wqb, wvb, wkb, bq, bv, bk, qb, outV, outK);
  // 3. P16 = exp(scores - 16) + row partial sums (longest-first)
  score_gemm<<<dim3(TQ / 128, TPAST / 128, BB), 256, 0, stream>>>(
      qb, kb, S16, sstride, l_part);
  // 4. out = (P16 @ VT) / rowsum (longest-first)
  pv_gemm<<<dim3(TQ / 128, CD / 128, BB), 256, 0, stream>>>(
      S16, vtb, out, sstride, l_part);
  // 5. fallback only: past_k -> outK rows [0,2048) after pv consumed S16
  if (!fit)
    copy_past_kernel<<<BB * TPAST * CD / 4 / 256, 256, 0, stream>>>(pk, outK);
}

// Round 17
// 199.656 us; speedup vs baseline: 1.7011x; 1.0015x over previous
//
#include <hip/hip_runtime.h>

// ---------------------------------------------------------------------------
// SelfAttention with KV cache, MI355X (gfx950).
// B=4, T=2048, C=1024, T_PAST=2048, T_TOT=4096.
// Mask tril(ones(T, T_total)) -> row t attends j<=t only => only past_k/v.
// Launches (main path, 4) [R13/R16 pipeline; this round: single-barrier core]:
//   1. prep: cvt x,Wq,Wk,Wv,past_k->bf16 (+ fused past_k->outK f32 copy)
//            + past_v->outV copy + VT bf16 transpose
//   2. proj_qkv (v2s): Q->qb; V_new->outV[2048+); K_new->outK[2048+)
//   3. score_gemm (v2s): P16 = bf16(exp(Q.kb^T - 16)) + row partial sums [LPT]
//   4. pv_gemm (v2s): out = (P16 @ VT) / rowsum  [LPT]
//
// GEMM core v2s (this round): 128x128 tile, BK=32, 4 waves, 3-slot LDS ring
// (48KB, 3 blocks/CU) -- SINGLE barrier per K-step. Prefetch depth 2 -> 1:
// stage(t+1) at iter t targets slot (t+1)%3, while reads(t)->t%3 and
// reads(t-1)->(t+2)%3 are both distinct, and lgkmcnt(0) retires each wave's
// reads before it can reach the next B1 -- so the old B2 (read-release
// barrier) is provably unnecessary at depth 1. vmcnt(4) mid-loop (never 0),
// vmcnt(0) only on the last step. XOR read-swizzle + pre-swizzled coalesced
// global source, lgkmcnt(0)+sched_barrier fence (rule 18), setprio(1) around
// the MFMA cluster. All other structure identical to the proven R13/R16 core.
// ---------------------------------------------------------------------------

typedef __bf16 bf16x8 __attribute__((ext_vector_type(8)));
typedef float f32x4 __attribute__((ext_vector_type(4)));

#define BB   4
#define TQ   2048
#define CD   1024
#define TPAST 2048
#define TTOT 4096
#define MROWS (BB * TQ)        // 8192
#define SSTRIDE_FALLBACK ((size_t)TTOT * CD * 2)  // u16 per batch window
#define SLOTU 8192             // u16 per ring slot (A 8KB + B 8KB)

__device__ __forceinline__ unsigned short f32_to_bf16u(float f) {
  unsigned int u = __float_as_uint(f);
  u += 0x7FFFu + ((u >> 16) & 1u);       // RNE
  return (unsigned short)(u >> 16);
}
__device__ __forceinline__ float bf16u_to_f32(unsigned short h) {
  unsigned int u = ((unsigned int)h) << 16;
  return __uint_as_float(u);
}
__device__ __forceinline__ unsigned int pack_bf16(float a, float b) {
  return (unsigned int)f32_to_bf16u(a) | ((unsigned int)f32_to_bf16u(b) << 16);
}
__device__ __forceinline__ void nt_store4(float4 f, float* p) {
  f32x4 v;
  v[0] = f.x; v[1] = f.y; v[2] = f.z; v[3] = f.w;
  __builtin_nontemporal_store(v, (f32x4*)p);
}

// async global->LDS, 16B per lane; LDS dest = wave-uniform base + lane*16
__device__ __forceinline__ void gload_lds16(const unsigned short* g,
                                            unsigned short* l) {
  __builtin_amdgcn_global_load_lds(
      (const __attribute__((address_space(1))) void*)g,
      (__attribute__((address_space(3))) void*)l, 16, 0, 0);
}

// ===========================================================================
// v2s core: 128x128, BK=32, 4 waves, 3-slot ring, depth-1, ONE barrier/step.
// ===========================================================================
struct StagePtrs { const unsigned short *a0, *a1, *b0, *b1; };

__device__ __forceinline__ void stage_step(StagePtrs& p, unsigned short* lds,
                                           int stOff, int wv) {
  unsigned short* base = lds + stOff + wv * 512;
  gload_lds16(p.a0, base);
  gload_lds16(p.a1, base + 2048);
  gload_lds16(p.b0, base + 4096);
  gload_lds16(p.b1, base + 6144);
  p.a0 += 32; p.a1 += 32; p.b0 += 32; p.b1 += 32;
}

__device__ __forceinline__ void gemm_core_v2(
    StagePtrs p, unsigned short* lds, int NT,
    int wr, int wc, int lane, int wv, f32x4 acc[4][4]) {
  const int gph8 = (((lane >> 4) ^ (lane & 3))) * 8;
  const int aRd = (wr * 64 + (lane & 15)) * 32 + gph8;
  const int bRd = 4096 + (wc * 64 + (lane & 15)) * 32 + gph8;
  stage_step(p, lds, 0, wv);                 // prologue: slot 0 only
  int stOff = SLOTU;                         // next stage target
  int rdOff = 0;
  for (int t = 0; t < NT; ++t) {
    if (t + 1 < NT) {
      stage_step(p, lds, stOff, wv);         // depth-1 prefetch of slot t+1
      stOff = (stOff == 2 * SLOTU) ? 0 : stOff + SLOTU;
      asm volatile("s_waitcnt vmcnt(4)" ::: "memory");   // slot t resident
    } else {
      asm volatile("s_waitcnt vmcnt(0)" ::: "memory");
    }
    asm volatile("s_barrier" ::: "memory");  // B1: the ONLY barrier per step
    bf16x8 af[4], bg[4];
#pragma unroll
    for (int i = 0; i < 4; ++i)
      af[i] = *(const bf16x8*)&lds[rdOff + aRd + i * 512];
#pragma unroll
    for (int i = 0; i < 4; ++i)
      bg[i] = *(const bf16x8*)&lds[rdOff + bRd + i * 512];
    asm volatile("s_waitcnt lgkmcnt(0)" ::: "memory");
    __builtin_amdgcn_sched_barrier(0);
    // no B2: at depth-1 the staged slot (t+1)%3 can never alias a slot any
    // wave may still read (t%3 now, (t+2)%3 one barrier ago -- both distinct),
    // and lgkmcnt(0) retires reads before the wave can reach the next B1.
    __builtin_amdgcn_s_setprio(1);
#pragma unroll
    for (int mi = 0; mi < 4; ++mi)
#pragma unroll
      for (int ni = 0; ni < 4; ++ni)
        acc[mi][ni] = __builtin_amdgcn_mfma_f32_16x16x32_bf16(
            af[mi], bg[ni], acc[mi][ni], 0, 0, 0);
    __builtin_amdgcn_s_setprio(0);
    rdOff = (rdOff == 2 * SLOTU) ? 0 : rdOff + SLOTU;
  }
}

// per-thread pre-swizzled source pointer for one operand tile.
__device__ __forceinline__ const unsigned short* swz_src(
    const unsigned short* base, size_t rowStart, size_t ld,
    int part, int wv, int lane) {
  int row = part * 64 + wv * 16 + (lane >> 2);
  int gp = (lane & 3) ^ ((lane >> 2) & 3);
  return base + (rowStart + row) * ld + gp * 8;
}

// ---- merged prep: v_copy_transpose blocks + cvt blocks (+pk f32 copy) ------
#define TP_PAD 134
#define VCT_BLOCKS 2048           // (2048/32) * (1024/128) * 4
#define R0_END 2097152            // x     : 8192*1024/4 f4
#define R1_END 2359296            // Wq    : +262144
#define R2_END 2621440            // Wk
#define R3_END 2883584            // Wv
#define R4_END 4980736            // past_k: +2097152
__global__ __launch_bounds__(256) void prep(
    const float* __restrict__ x, const float* __restrict__ wq,
    const float* __restrict__ wk, const float* __restrict__ wv,
    const float* __restrict__ pk, const float* __restrict__ pV,
    unsigned short* __restrict__ xb, unsigned short* __restrict__ wqb,
    unsigned short* __restrict__ wkb, unsigned short* __restrict__ wvb,
    unsigned short* __restrict__ kb,
    float* __restrict__ outV, unsigned short* __restrict__ VT,
    float* __restrict__ outKcopy) {   // nullptr -> skip pk f32 copy
  const int tid = threadIdx.x;
  if (blockIdx.x < VCT_BLOCKS) {
    __shared__ unsigned short T[32 * TP_PAD];
    const int bid = blockIdx.x;
    const int s0 = (bid & 63) * 32, c0 = ((bid >> 6) & 7) * 128, b = bid >> 9;
    const int s = tid >> 3, i8 = tid & 7;
    const float* src = &pV[(size_t)(b * TPAST + s0 + s) * CD + c0];
    float* dst = &outV[(size_t)b * (TTOT * CD) + (size_t)(s0 + s) * CD + c0];
#pragma unroll
    for (int k = 0; k < 4; ++k) {
      int c = k * 32 + i8 * 4;
      float4 f = *(const float4*)&src[c];
      nt_store4(f, &dst[c]);                  // pure output
      *(unsigned int*)&T[s * TP_PAD + c]     = pack_bf16(f.x, f.y);
      *(unsigned int*)&T[s * TP_PAD + c + 2] = pack_bf16(f.z, f.w);
    }
    __syncthreads();
    const int c = tid >> 2, sq = tid & 3;
#pragma unroll
    for (int ii = 0; ii < 2; ++ii) {
      int cc = c + ii * 64;
      unsigned short tmp[8];
#pragma unroll
      for (int j = 0; j < 8; ++j) tmp[j] = T[(sq * 8 + j) * TP_PAD + cc];
      *(uint4*)&VT[(size_t)(b * CD + c0 + cc) * TPAST + s0 + sq * 8] = *(uint4*)tmp;
    }
    return;
  }
  int i = (blockIdx.x - VCT_BLOCKS) * 256 + tid;
  const float* src; unsigned short* dst; int off;
  bool isPk = false;
  if (i < R0_END)      { src = x;  dst = xb;  off = i; }
  else if (i < R1_END) { src = wq; dst = wqb; off = i - R0_END; }
  else if (i < R2_END) { src = wk; dst = wkb; off = i - R1_END; }
  else if (i < R3_END) { src = wv; dst = wvb; off = i - R2_END; }
  else                 { src = pk; dst = kb;  off = i - R3_END; isPk = true; }
  float4 f = ((const float4*)src)[off];
  uint2 o;
  o.x = pack_bf16(f.x, f.y);
  o.y = pack_bf16(f.z, f.w);
  ((uint2*)dst)[off] = o;
  if (isPk && outKcopy) {
    int b = off >> 19;                 // 524288 f4-units per batch
    int rem = off & 524287;
    nt_store4(f, outKcopy + ((size_t)b * 1048576 + rem) * 4); // rows [0,2048)
  }
}

// ---- fallback: copy past_k into cache region rows [0,2048) -----------------
__global__ __launch_bounds__(256) void copy_past_kernel(
    const float* __restrict__ src, float* __restrict__ dst) {
  int i = blockIdx.x * 256 + threadIdx.x;      // float4 units
  int b = i >> 19;
  int rem = i & 524287;
  ((float4*)dst)[(size_t)b * 1048576 + rem] = ((const float4*)src)[i];
}

// ---- merged Q+V+K projection (v2s core) -------------------------------------
__global__ __launch_bounds__(256, 3) void proj_qkv(
    const unsigned short* __restrict__ A,    // x bf16 [8192][1024]
    const unsigned short* __restrict__ Wq_,
    const unsigned short* __restrict__ Wv_,
    const unsigned short* __restrict__ Wk_,
    const float* __restrict__ bq_, const float* __restrict__ bv_,
    const float* __restrict__ bk_,
    unsigned short* __restrict__ outQ,
    float* __restrict__ outV, float* __restrict__ outK) {
  __shared__ unsigned short lds[3 * SLOTU];
  const int tm = blockIdx.x * 128;
  const int which = blockIdx.y >> 3;         // 0=Q, 1=V, 2=K
  const int tn = (blockIdx.y & 7) * 128;
  const unsigned short* W = (which == 0) ? Wq_ : (which == 1) ? Wv_ : Wk_;
  const float* bias = (which == 0) ? bq_ : (which == 1) ? bv_ : bk_;
  const int tid = threadIdx.x, lane = tid & 63, wv = tid >> 6;
  const int wr = wv >> 1, wc = wv & 1;
  StagePtrs p;
  p.a0 = swz_src(A, tm, CD, 0, wv, lane);
  p.a1 = swz_src(A, tm, CD, 1, wv, lane);
  p.b0 = swz_src(W, tn, CD, 0, wv, lane);
  p.b1 = swz_src(W, tn, CD, 1, wv, lane);
  f32x4 acc[4][4] = {};
  gemm_core_v2(p, lds, CD / 32, wr, wc, lane, wv, acc);
  const int rsub = (lane >> 4) * 4, csub = lane & 15;
#pragma unroll
  for (int mi = 0; mi < 4; ++mi)
#pragma unroll
    for (int ni = 0; ni < 4; ++ni) {
      int gcn = tn + wc * 64 + ni * 16 + csub;
      float bvv = bias[gcn];
#pragma unroll
      for (int r = 0; r < 4; ++r) {
        int grw = tm + wr * 64 + mi * 16 + rsub + r;
        float v = acc[mi][ni][r] + bvv;
        if (which == 0) {
          outQ[(size_t)grw * CD + gcn] = f32_to_bf16u(v * 0.03125f);  // 1/sqrt(1024)
        } else {
          int b = grw >> 11, t = grw & (TQ - 1);
          float* o = (which == 1) ? outV : outK;
          __builtin_nontemporal_store(
              v, &o[(size_t)b * (TTOT * CD) + (size_t)(TPAST + t) * CD + gcn]);
        }
      }
    }
}

// ---- scores: P16 = bf16(exp(Q.kb^T - 16)), masked cols -> 0 -----------------
// Longest-row-first: t0 = (15 - bx)*128 (LPT scheduling for the causal skip).
__global__ __launch_bounds__(256, 3) void score_gemm(
    const unsigned short* __restrict__ Q,
    const unsigned short* __restrict__ KB,
    unsigned short* __restrict__ S16, size_t sstride,
    float* __restrict__ l_part) {            // [4][2048][16] f32
  const int t0 = (TQ / 128 - 1 - blockIdx.x) * 128;
  const int s0 = blockIdx.y * 128, b = blockIdx.z;
  if (s0 > t0) return;                       // fully masked tile
  __shared__ unsigned short lds[3 * SLOTU];
  __shared__ float lpart[128][2];
  const int tid = threadIdx.x, lane = tid & 63, wv = tid >> 6;
  const int wr = wv >> 1, wc = wv & 1;
  StagePtrs p;
  p.a0 = swz_src(Q, (size_t)b * TQ + t0, CD, 0, wv, lane);
  p.a1 = swz_src(Q, (size_t)b * TQ + t0, CD, 1, wv, lane);
  p.b0 = swz_src(KB, (size_t)b * TPAST + s0, CD, 0, wv, lane);
  p.b1 = swz_src(KB, (size_t)b * TPAST + s0, CD, 1, wv, lane);
  f32x4 acc[4][4] = {};
  gemm_core_v2(p, lds, CD / 32, wr, wc, lane, wv, acc);
  const int rsub = (lane >> 4) * 4, csub = lane & 15;
  float rsum[4][4];
#pragma unroll
  for (int mi = 0; mi < 4; ++mi)
#pragma unroll
    for (int r = 0; r < 4; ++r) rsum[mi][r] = 0.f;
#pragma unroll
  for (int mi = 0; mi < 4; ++mi)
#pragma unroll
    for (int ni = 0; ni < 4; ++ni) {
      int gs = s0 + wc * 64 + ni * 16 + csub;
#pragma unroll
      for (int r = 0; r < 4; ++r) {
        int gt = t0 + wr * 64 + mi * 16 + rsub + r;
        float e = (gs <= gt) ? __expf(acc[mi][ni][r] - 16.f) : 0.f;
        unsigned short h = f32_to_bf16u(e);
        S16[(size_t)b * sstride + (size_t)gt * TPAST + gs] = h;
        rsum[mi][r] += bf16u_to_f32(h);      // match numerator quantization
      }
    }
#pragma unroll
  for (int mi = 0; mi < 4; ++mi)
#pragma unroll
    for (int r = 0; r < 4; ++r) {
      float v = rsum[mi][r];
      v += __shfl_xor(v, 1);
      v += __shfl_xor(v, 2);
      v += __shfl_xor(v, 4);
      v += __shfl_xor(v, 8);
      rsum[mi][r] = v;                       // sum over 16 csub lanes
    }
  if ((lane & 15) == 0) {
#pragma unroll
    for (int mi = 0; mi < 4; ++mi)
#pragma unroll
      for (int r = 0; r < 4; ++r)
        lpart[wr * 64 + mi * 16 + rsub + r][wc] = rsum[mi][r];
  }
  __syncthreads();
  if (tid < 128)
    l_part[((size_t)b * TQ + t0 + tid) * 16 + (s0 >> 7)] =
        lpart[tid][0] + lpart[tid][1];
}

// ---- out = (P16 @ VT) / rowsum (v2s core) ------------------------------------
// Longest-K-first: t0 = (15 - bx)*128 (K extent = t0+128; LPT scheduling).
__global__ __launch_bounds__(256, 3) void pv_gemm(
    const unsigned short* __restrict__ Pb,  // bf16 exp values
    const unsigned short* __restrict__ VT,  // bf16 [4][1024][2048]
    float* __restrict__ O, size_t sstride,
    const float* __restrict__ l_part) {
  const int t0 = (TQ / 128 - 1 - blockIdx.x) * 128;
  const int c0 = blockIdx.y * 128, b = blockIdx.z;
  __shared__ unsigned short lds[3 * SLOTU];
  const int tid = threadIdx.x, lane = tid & 63, wv = tid >> 6;
  const int wr = wv >> 1, wc = wv & 1;
  StagePtrs p;
  p.a0 = swz_src(Pb + (size_t)b * sstride, t0, TPAST, 0, wv, lane);
  p.a1 = swz_src(Pb + (size_t)b * sstride, t0, TPAST, 1, wv, lane);
  p.b0 = swz_src(VT, (size_t)b * CD + c0, TPAST, 0, wv, lane);
  p.b1 = swz_src(VT, (size_t)b * CD + c0, TPAST, 1, wv, lane);
  f32x4 acc[4][4] = {};
  const int s_end = (t0 + 128 < TPAST) ? (t0 + 128) : TPAST;  // P==0 past t
  gemm_core_v2(p, lds, s_end / 32, wr, wc, lane, wv, acc);
  // --- row normalization factors: 1 / sum_j l_part[b][t][j], j <= t0>>7 ---
  __syncthreads();
  float* linv = (float*)lds;                 // reuse ring LDS
  if (tid < 128) {
    const float* lp = &l_part[((size_t)b * TQ + t0 + tid) * 16];
    float s = 0.f;
    const int nj = (t0 >> 7) + 1;
    for (int j = 0; j < nj; ++j) s += lp[j];
    linv[tid] = 1.0f / s;
  }
  __syncthreads();
  const int rsub = (lane >> 4) * 4, csub = lane & 15;
#pragma unroll
  for (int mi = 0; mi < 4; ++mi)
#pragma unroll
    for (int ni = 0; ni < 4; ++ni) {
      int gcn = c0 + wc * 64 + ni * 16 + csub;
#pragma unroll
      for (int r = 0; r < 4; ++r) {
        int lrow = wr * 64 + mi * 16 + rsub + r;
        int gt = t0 + lrow;
        __builtin_nontemporal_store(
            acc[mi][ni][r] * linv[lrow], &O[(size_t)(b * TQ + gt) * CD + gcn]);
      }
    }
}

extern "C" void kernel_launch(void* const* d_in, const int* in_sizes, int n_in,
                              void* d_out, int out_size, void* d_ws, size_t ws_size,
                              hipStream_t stream) {
  const float* x  = (const float*)d_in[0];
  const float* pk = (const float*)d_in[1];
  const float* pv = (const float*)d_in[2];
  const float* Wq = (const float*)d_in[3];
  const float* bq = (const float*)d_in[4];
  const float* Wk = (const float*)d_in[5];
  const float* bk = (const float*)d_in[6];
  const float* Wv = (const float*)d_in[7];
  const float* bv = (const float*)d_in[8];

  float* out  = (float*)d_out;                       // (4,2048,1024)
  float* outK = out + (size_t)BB * TQ * CD;          // (4,4096,1024)
  float* outV = outK + (size_t)BB * TTOT * CD;       // (4,4096,1024)

  unsigned short* xb  = (unsigned short*)d_ws;       // 8192*1024 bf16
  unsigned short* wqb = xb + (size_t)MROWS * CD;
  unsigned short* wkb = wqb + (size_t)CD * CD;
  unsigned short* wvb = wkb + (size_t)CD * CD;
  unsigned short* qb  = wvb + (size_t)CD * CD;       // 8192*1024 bf16
  unsigned short* vtb = qb + (size_t)MROWS * CD;     // 4*1024*2048 bf16 (V^T)
  unsigned short* kb  = vtb + (size_t)BB * CD * TPAST; // 4*2048*1024 bf16
  unsigned short* wsEnd = kb + (size_t)BB * TPAST * CD;

  // S16 (4*2048*2048 bf16 = 33.5MB) + l_part (4*2048*16 f32 = 0.5MB)
  const size_t baseBytes = (size_t)((char*)wsEnd - (char*)d_ws);
  const size_t s16Bytes  = (size_t)BB * TQ * TPAST * 2;
  const size_t lpBytes   = (size_t)BB * TQ * 16 * 4;
  const bool fit = ws_size >= baseBytes + s16Bytes + lpBytes;

  unsigned short* S16;
  float* l_part;
  size_t sstride;
  if (fit) {
    S16 = wsEnd;
    l_part = (float*)(S16 + (size_t)BB * TQ * TPAST);
    sstride = (size_t)TQ * TPAST;            // dense per-batch stride
  } else {
    S16 = (unsigned short*)outK;             // overlay rows [0,2048)/batch
    l_part = (float*)wsEnd;
    sstride = SSTRIDE_FALLBACK;
  }

  // 1. conversions + past_v copy/transpose (+ past_k f32 copy when S16 in ws)
  prep<<<VCT_BLOCKS + R4_END / 256, 256, 0, stream>>>(
      x, Wq, Wk, Wv, pk, pv, xb, wqb, wkb, wvb, kb, outV, vtb,
      fit ? outK : nullptr);
  // 2. Q (bf16, scaled) + V_new + K_new (rows 2048+)
  proj_qkv<<<dim3(MROWS / 128, 24), 256, 0, stream>>>(
      xb, wqb, wvb, wkb, bq, bv, bk, qb, outV, outK);
  // 3. P16 = exp(scores - 16) + row partial sums (longest-first)
  score_gemm<<<dim3(TQ / 128, TPAST / 128, BB), 256, 0, stream>>>(
      qb, kb, S16, sstride, l_part);
  // 4. out = (P16 @ VT) / rowsum (longest-first)
  pv_gemm<<<dim3(TQ / 128, CD / 128, BB), 256, 0, stream>>>(
      S16, vtb, out, sstride, l_part);
  // 5. fallback only: past_k -> outK rows [0,2048) after pv consumed S16
  if (!fit)
    copy_past_kernel<<<BB * TPAST * CD / 4 / 256, 256, 0, stream>>>(pk, outK);
}